// Round 8
// baseline (116.537 us; speedup 1.0000x reference)
//
#include <hip/hip_runtime.h>

#define LSEQ 8192
#define E 1024
#define H 16
#define NSHARD 16
#define NCHUNK 128

typedef __attribute__((ext_vector_type(8))) short short8;
typedef __attribute__((ext_vector_type(4))) float f32x4;

__device__ inline float bf2f(unsigned int u16) {
    union { unsigned int i; float f; } v;
    v.i = (u16 & 0xffffu) << 16;
    return v.f;
}

__device__ inline unsigned short f2bf(float f) {
    union { float f; unsigned int i; } v; v.f = f;
    unsigned int x = v.i;
    return (unsigned short)((x + 0x7fffu + ((x >> 16) & 1u)) >> 16);
}

__device__ inline float wave_reduce_sum(float v) {
    #pragma unroll
    for (int off = 32; off > 0; off >>= 1) v += __shfl_xor(v, off, 64);
    return v;
}

// k0: q[i] = Wq[i,:].x0 + bq[i]. One wave per output; block 0 zeroes S_shard.
__global__ __launch_bounds__(256) void k0_q(
    const float* __restrict__ x, const float* __restrict__ W,
    const float* __restrict__ bias, float* __restrict__ q_ws,
    float* __restrict__ S_shard)
{
    if (blockIdx.x == 0) S_shard[threadIdx.x] = 0.f;   // 256 = NSHARD*16
    int wave = threadIdx.x >> 6, lane = threadIdx.x & 63;
    int i = blockIdx.x * 4 + wave;
    const f32x4* wp = (const f32x4*)(W + i * E) + lane * 4;
    const f32x4* xp = (const f32x4*)(x) + lane * 4;
    float s = 0.f;
    #pragma unroll
    for (int j = 0; j < 4; j++) {
        f32x4 w4 = wp[j], x4 = xp[j];
        s += w4[0]*x4[0] + w4[1]*x4[1] + w4[2]*x4[2] + w4[3]*x4[3];
    }
    s = wave_reduce_sum(s);
    if (lane == 0) q_ws[i] = s + bias[i];
}

// k1: r_bf[h][e] = bf16(0.125 * Wk_h^T q_h); c[h] = 0.125 * q_h . bk_h
__global__ __launch_bounds__(256) void k1_rc(
    const float* __restrict__ W, const float* __restrict__ bias,
    const float* __restrict__ q_ws, unsigned short* __restrict__ r_bf,
    float* __restrict__ c_ws)
{
    __shared__ float red[4][64];
    int hb = blockIdx.x >> 4, ec = blockIdx.x & 15;
    int lane = threadIdx.x & 63, wq = threadIdx.x >> 6;
    int e = ec * 64 + lane;
    const float* qh = q_ws + hb * 64;
    float acc = 0.f;
    #pragma unroll
    for (int i = 0; i < 16; i++) {
        int d = wq * 16 + i;
        acc += qh[d] * W[(E + hb * 64 + d) * E + e];
    }
    red[wq][lane] = acc;
    __syncthreads();
    if (wq == 0) {
        float s = red[0][lane] + red[1][lane] + red[2][lane] + red[3][lane];
        r_bf[hb * E + e] = f2bf(s * 0.125f);
    }
    if (ec == 0 && wq == 1) {
        float v = qh[lane] * bias[E + hb * 64 + lane];
        v = wave_reduce_sum(v);
        if (lane == 0) c_ws[hb] = v * 0.125f;
    }
}

// k2: single pass over x. 128 blocks x 1024 threads; block beta owns rows
// [beta*64, beta*64+64) as 4 tiles of 16 rows, with register prefetch of the
// next tile overlapping the MFMA/exp phases.
//   scores via MFMA -> p = exp(score) (no max; scores ~ N(0,1))
//   -> register u-partials (1 col x 16 heads/thread)
//   -> shfl-packed bf16 store (4 MB total, no atomics)
//   -> S_shard[beta&15] += esum
__global__ __launch_bounds__(1024, 1) void k2_fused(
    const float* __restrict__ x,
    const unsigned short* __restrict__ r_bf,
    const float* __restrict__ c_ws,
    unsigned int* __restrict__ partial_bf, float* __restrict__ S_shard)
{
    __shared__ float x_lds[16 * 1028];    // 16 rows, stride 1028 (pad 4)
    __shared__ float sp[16 * 64 * 4];     // per-wave MFMA partials (16 KB)
    __shared__ float p_lds[16 * 16];      // [row][head]
    __shared__ float esum[16];

    const int tid  = threadIdx.x;
    const int wave = tid >> 6, lane = tid & 63;
    const int beta = blockIdx.x;
    const int lbase = beta * 64;

    if (tid < 16) esum[tid] = 0.f;
    float acc[16];    // 16 heads x 1 col (col = tid)
    #pragma unroll
    for (int i = 0; i < 16; i++) acc[i] = 0.f;

    // staging assignment: row = tid>>6 (16 rows x 64 threads), 4 f32x4 each
    const int srow = tid >> 6, sch = tid & 63;
    f32x4 pre[4];
    {
        const f32x4* src = (const f32x4*)(x + (lbase + srow) * E);
        #pragma unroll
        for (int j = 0; j < 4; j++) pre[j] = src[sch + 64 * j];
    }

    for (int t = 0; t < 4; t++) {
        __syncthreads();   // prior accumulate done reading x_lds/p_lds
        // write prefetched tile to LDS
        {
            float* dst = x_lds + srow * 1028;
            #pragma unroll
            for (int j = 0; j < 4; j++) *(f32x4*)(dst + (sch + 64 * j) * 4) = pre[j];
        }
        // issue next tile's loads (complete under MFMA/exp)
        {
            int nt = (t + 1) & 3;
            const f32x4* src = (const f32x4*)(x + (lbase + nt * 16 + srow) * E);
            #pragma unroll
            for (int j = 0; j < 4; j++) pre[j] = src[sch + 64 * j];
        }
        __syncthreads();
        // MFMA: wave w covers K window [w*64, w*64+64)
        {
            int rw = lane & 15, quad = lane >> 4;
            f32x4 sacc = {0.f, 0.f, 0.f, 0.f};
            const float* arow = x_lds + rw * 1028 + wave * 64 + quad * 8;
            const short8* bp = (const short8*)(r_bf + rw * E + wave * 64 + quad * 8);
            #pragma unroll
            for (int kk = 0; kk < 2; kk++) {
                f32x4 a0 = *(const f32x4*)(arow + kk * 32);
                f32x4 a1 = *(const f32x4*)(arow + kk * 32 + 4);
                short8 af;
                af[0] = (short)f2bf(a0[0]); af[1] = (short)f2bf(a0[1]);
                af[2] = (short)f2bf(a0[2]); af[3] = (short)f2bf(a0[3]);
                af[4] = (short)f2bf(a1[0]); af[5] = (short)f2bf(a1[1]);
                af[6] = (short)f2bf(a1[2]); af[7] = (short)f2bf(a1[3]);
                short8 bfr = bp[kk * 4];
                sacc = __builtin_amdgcn_mfma_f32_16x16x32_bf16(af, bfr, sacc, 0, 0, 0);
            }
            *(f32x4*)&sp[(wave * 64 + lane) * 4] = sacc;
        }
        __syncthreads();
        // p = exp(score)  (C/D layout: col=lane&15, row=quad*4+reg)
        if (tid < 256) {
            int m = tid >> 4, hh = tid & 15;
            int ln = (m >> 2) * 16 + hh, rg = m & 3;
            float s = c_ws[hh];
            #pragma unroll
            for (int w = 0; w < 16; w++) s += sp[(w * 64 + ln) * 4 + rg];
            float p = __expf(s);
            p_lds[m * 16 + hh] = p;
            atomicAdd(&esum[hh], p);
        }
        __syncthreads();
        // accumulate u partial: thread owns col tid x 16 heads
        #pragma unroll 4
        for (int m = 0; m < 16; m++) {
            float xv = x_lds[m * 1028 + tid];
            const f32x4* pp = (const f32x4*)&p_lds[m * 16];
            #pragma unroll
            for (int g = 0; g < 4; g++) {
                f32x4 pv = pp[g];
                acc[g * 4 + 0] += pv[0] * xv;
                acc[g * 4 + 1] += pv[1] * xv;
                acc[g * 4 + 2] += pv[2] * xv;
                acc[g * 4 + 3] += pv[3] * xv;
            }
        }
    }
    __syncthreads();
    // pack pairs of cols to dwords via lane shuffle; even lanes store
    {
        unsigned int* pb = partial_bf + beta * (H * 512);
        #pragma unroll
        for (int h = 0; h < 16; h++) {
            unsigned int mine = (unsigned int)f2bf(acc[h]);
            unsigned int other = (unsigned int)__shfl_xor((int)mine, 1, 64);
            if ((tid & 1) == 0) pb[h * 512 + (tid >> 1)] = mine | (other << 16);
        }
        if (tid < 16) atomicAdd(&S_shard[(beta & 15) * 16 + tid], esum[tid]);
    }
}

// k3: u[2c..2c+1] = sum over 128 chunks of packed-bf16 partial col c.
// 128 blocks x 512 thr; each block owns 64 uint cols (128 fp32 outputs).
__global__ __launch_bounds__(512) void k3_reduce(
    const unsigned int* __restrict__ partial_bf, float2* __restrict__ u_ws2)
{
    __shared__ float red[8][64][2];
    int wave = threadIdx.x >> 6, lane = threadIdx.x & 63;
    int col = blockIdx.x * 64 + lane;        // 0..8191 uint columns
    float s0 = 0.f, s1 = 0.f;
    #pragma unroll 8
    for (int bb = wave; bb < NCHUNK; bb += 8) {
        unsigned int v = partial_bf[bb * 8192 + col];
        s0 += bf2f(v);
        s1 += bf2f(v >> 16);
    }
    red[wave][lane][0] = s0;
    red[wave][lane][1] = s1;
    __syncthreads();
    if (wave == 0) {
        float t0 = 0.f, t1 = 0.f;
        #pragma unroll
        for (int w = 0; w < 8; w++) { t0 += red[w][lane][0]; t1 += red[w][lane][1]; }
        float2 o; o.x = t0; o.y = t1;
        u_ws2[col] = o;
    }
}

// k4: oh[i] = (Wv[i,:].u_h)/S_h + bv[i]. One wave per output.
__global__ __launch_bounds__(256) void k4_oh(
    const float* __restrict__ W, const float* __restrict__ bias,
    const float* __restrict__ u_ws, const float* __restrict__ S_shard,
    float* __restrict__ oh_ws)
{
    int wave = threadIdx.x >> 6, lane = threadIdx.x & 63;
    int i = blockIdx.x * 4 + wave;
    int h = i >> 6;
    float Sh = 0.f;
    #pragma unroll
    for (int sh = 0; sh < NSHARD; sh++) Sh += S_shard[sh * 16 + h];
    const f32x4* wp = (const f32x4*)(W + (2 * E + i) * E) + lane * 4;
    const f32x4* up = (const f32x4*)(u_ws + h * E) + lane * 4;
    float s = 0.f;
    #pragma unroll
    for (int j = 0; j < 4; j++) {
        f32x4 w4 = wp[j], u4 = up[j];
        s += w4[0]*u4[0] + w4[1]*u4[1] + w4[2]*u4[2] + w4[3]*u4[3];
    }
    s = wave_reduce_sum(s);
    if (lane == 0) oh_ws[i] = s / Sh + bias[2 * E + i];
}

// k5: out[j] = Wout[j,:].oh + bout[j]. One wave per output.
__global__ __launch_bounds__(256) void k5_out(
    const float* __restrict__ Wout, const float* __restrict__ bout,
    const float* __restrict__ oh_ws, float* __restrict__ out)
{
    int wave = threadIdx.x >> 6, lane = threadIdx.x & 63;
    int j = blockIdx.x * 4 + wave;
    const f32x4* wp = (const f32x4*)(Wout + j * E) + lane * 4;
    const f32x4* op = (const f32x4*)(oh_ws) + lane * 4;
    float s = 0.f;
    #pragma unroll
    for (int jj = 0; jj < 4; jj++) {
        f32x4 w4 = wp[jj], o4 = op[jj];
        s += w4[0]*o4[0] + w4[1]*o4[1] + w4[2]*o4[2] + w4[3]*o4[3];
    }
    s = wave_reduce_sum(s);
    if (lane == 0) out[j] = s + bout[j];
}

extern "C" void kernel_launch(void* const* d_in, const int* in_sizes, int n_in,
                              void* d_out, int out_size, void* d_ws, size_t ws_size,
                              hipStream_t stream) {
    const float* x  = (const float*)d_in[0];
    const float* W  = (const float*)d_in[1];
    const float* b  = (const float*)d_in[2];
    const float* Wo = (const float*)d_in[3];
    const float* bo = (const float*)d_in[4];
    float* out = (float*)d_out;
    char* ws = (char*)d_ws;

    float* c_ws    = (float*)(ws);                  // 64 B
    float* S_shard = (float*)(ws + 1024);           // 1 KB (16 shards x 16 h)
    float* oh_ws   = (float*)(ws + 4096);           // 4 KB
    float* q_ws    = (float*)(ws + 12288);          // 4 KB
    unsigned short* r_bf = (unsigned short*)(ws + 16384); // 32 KB
    float* u_ws    = (float*)(ws + 65536);          // 64 KB
    unsigned int* partial_bf = (unsigned int*)(ws + 131072);  // 4 MB

    hipLaunchKernelGGL(k0_q,     dim3(256), dim3(256), 0, stream,
                       x, W, b, q_ws, S_shard);
    hipLaunchKernelGGL(k1_rc,    dim3(256), dim3(256), 0, stream,
                       W, b, q_ws, r_bf, c_ws);
    hipLaunchKernelGGL(k2_fused, dim3(128), dim3(1024), 0, stream,
                       x, r_bf, c_ws, partial_bf, S_shard);
    hipLaunchKernelGGL(k3_reduce, dim3(128), dim3(512), 0, stream,
                       partial_bf, (float2*)u_ws);
    hipLaunchKernelGGL(k4_oh,    dim3(256), dim3(256), 0, stream,
                       W, b, u_ws, S_shard, oh_ws);
    hipLaunchKernelGGL(k5_out,   dim3(256), dim3(256), 0, stream,
                       Wo, bo, oh_ws, out);
}

// Round 9
// 108.431 us; speedup vs baseline: 1.0748x; 1.0748x over previous
//
#include <hip/hip_runtime.h>

#define LSEQ 8192
#define E 1024
#define H 16
#define NSHARD 16

typedef __attribute__((ext_vector_type(8))) short short8;
typedef __attribute__((ext_vector_type(4))) float f32x4;

__device__ inline float bf2f(unsigned int u16) {
    union { unsigned int i; float f; } v;
    v.i = (u16 & 0xffffu) << 16;
    return v.f;
}

__device__ inline unsigned short f2bf(float f) {
    union { float f; unsigned int i; } v; v.f = f;
    unsigned int x = v.i;
    return (unsigned short)((x + 0x7fffu + ((x >> 16) & 1u)) >> 16);
}

__device__ inline float wave_reduce_sum(float v) {
    #pragma unroll
    for (int off = 32; off > 0; off >>= 1) v += __shfl_xor(v, off, 64);
    return v;
}

// k0: q[i] = Wq[i,:].x0 + bq[i]. One wave per output; block 0 zeroes S_shard.
__global__ __launch_bounds__(256) void k0_q(
    const float* __restrict__ x, const float* __restrict__ W,
    const float* __restrict__ bias, float* __restrict__ q_ws,
    float* __restrict__ S_shard)
{
    if (blockIdx.x == 0) S_shard[threadIdx.x] = 0.f;   // 256 = NSHARD*16
    int wave = threadIdx.x >> 6, lane = threadIdx.x & 63;
    int i = blockIdx.x * 4 + wave;
    const f32x4* wp = (const f32x4*)(W + i * E) + lane * 4;
    const f32x4* xp = (const f32x4*)(x) + lane * 4;
    float s = 0.f;
    #pragma unroll
    for (int j = 0; j < 4; j++) {
        f32x4 w4 = wp[j], x4 = xp[j];
        s += w4[0]*x4[0] + w4[1]*x4[1] + w4[2]*x4[2] + w4[3]*x4[3];
    }
    s = wave_reduce_sum(s);
    if (lane == 0) q_ws[i] = s + bias[i];
}

// k1: r_bf[h][e] = bf16(0.125 * Wk_h^T q_h); c[h] = 0.125 * q_h . bk_h
__global__ __launch_bounds__(256) void k1_rc(
    const float* __restrict__ W, const float* __restrict__ bias,
    const float* __restrict__ q_ws, unsigned short* __restrict__ r_bf,
    float* __restrict__ c_ws)
{
    __shared__ float red[4][64];
    int hb = blockIdx.x >> 4, ec = blockIdx.x & 15;
    int lane = threadIdx.x & 63, wq = threadIdx.x >> 6;
    int e = ec * 64 + lane;
    const float* qh = q_ws + hb * 64;
    float acc = 0.f;
    #pragma unroll
    for (int i = 0; i < 16; i++) {
        int d = wq * 16 + i;
        acc += qh[d] * W[(E + hb * 64 + d) * E + e];
    }
    red[wq][lane] = acc;
    __syncthreads();
    if (wq == 0) {
        float s = red[0][lane] + red[1][lane] + red[2][lane] + red[3][lane];
        r_bf[hb * E + e] = f2bf(s * 0.125f);
    }
    if (ec == 0 && wq == 1) {
        float v = qh[lane] * bias[E + hb * 64 + lane];
        v = wave_reduce_sum(v);
        if (lane == 0) c_ws[hb] = v * 0.125f;
    }
}

// k2: single pass over x. 256 blocks x 512 threads; block beta owns rows
// [beta*32, beta*32+32) as TWO 16-row tiles processed by CONCURRENT wave
// groups (waves 0-3 -> tile 0, waves 4-7 -> tile 1). 3 barriers total.
//   scores via MFMA -> p = exp(score) (no max; scores ~ N(0,1))
//   -> register u-partials (2 cols x 16 heads/thread over all 32 rows)
//   -> packed bf16 store (8 MB total, no atomics)
//   -> S_shard[beta&15] += esum
__global__ __launch_bounds__(512, 1) void k2_fused(
    const float* __restrict__ x,
    const unsigned short* __restrict__ r_bf,
    const float* __restrict__ c_ws,
    unsigned int* __restrict__ partial_bf, float* __restrict__ S_shard)
{
    __shared__ float x_lds[2 * 16 * 1028];  // group g at g*16448, pad 4/row
    __shared__ float sp[2 * 4 * 64 * 4];    // per-wave MFMA partials
    __shared__ float p_lds[2 * 256];        // [group][row*16+head]
    __shared__ float esum[16];

    const int tid  = threadIdx.x;
    const int wave = tid >> 6, lane = tid & 63;
    const int g = tid >> 8;                 // wave group = tile index
    const int wq = wave & 3;                // wave within group
    const int beta = blockIdx.x;
    const int R0 = beta * 32 + g * 16;

    if (tid < 16) esum[tid] = 0.f;

    // stage: each group's 256 threads load its 16 rows (16 thr/row x 16 f32x4)
    {
        int gt = tid & 255;
        int row = gt >> 4, ch = gt & 15;
        const f32x4* src = (const f32x4*)(x + (R0 + row) * E);
        f32x4* dst = (f32x4*)(x_lds + g * 16448 + row * 1028);
        #pragma unroll
        for (int j = 0; j < 16; j++) {
            // dst stride is in floats; write via float* to honor pad
            *(f32x4*)((float*)(x_lds + g * 16448 + row * 1028) + (ch + 16 * j) * 4)
                = src[ch + 16 * j];
        }
        (void)dst;
    }
    __syncthreads();

    // MFMA: wave (g,wq) covers K window [wq*256, wq*256+256) of its tile
    {
        int rw = lane & 15, quad = lane >> 4;
        f32x4 sacc = {0.f, 0.f, 0.f, 0.f};
        const float* arow = x_lds + g * 16448 + rw * 1028 + wq * 256 + quad * 8;
        const short8* bp = (const short8*)(r_bf + rw * E + wq * 256 + quad * 8);
        #pragma unroll
        for (int kk = 0; kk < 8; kk++) {
            f32x4 a0 = *(const f32x4*)(arow + kk * 32);
            f32x4 a1 = *(const f32x4*)(arow + kk * 32 + 4);
            short8 af;
            af[0] = (short)f2bf(a0[0]); af[1] = (short)f2bf(a0[1]);
            af[2] = (short)f2bf(a0[2]); af[3] = (short)f2bf(a0[3]);
            af[4] = (short)f2bf(a1[0]); af[5] = (short)f2bf(a1[1]);
            af[6] = (short)f2bf(a1[2]); af[7] = (short)f2bf(a1[3]);
            short8 bfr = bp[kk * 4];
            sacc = __builtin_amdgcn_mfma_f32_16x16x32_bf16(af, bfr, sacc, 0, 0, 0);
        }
        *(f32x4*)&sp[(wave * 64 + lane) * 4] = sacc;
    }
    __syncthreads();

    // exp: all 512 threads; tid maps to (group, row m, head hh)
    // C/D layout: col=lane&15 (head), row = quad*4 + reg
    {
        int m = (tid >> 4) & 15, hh = tid & 15;
        int ln = (m >> 2) * 16 + hh, rg = m & 3;
        float s = c_ws[hh];
        #pragma unroll
        for (int w = 0; w < 4; w++) s += sp[((g * 4 + w) * 64 + ln) * 4 + rg];
        float p = __expf(s);
        p_lds[g * 256 + m * 16 + hh] = p;
        atomicAdd(&esum[hh], p);
    }
    __syncthreads();

    // accumulate u partial over all 32 rows: thread owns 2 cols x 16 heads
    float acc[32];
    #pragma unroll
    for (int i = 0; i < 32; i++) acc[i] = 0.f;
    #pragma unroll 4
    for (int mi = 0; mi < 32; mi++) {
        int gg = mi >> 4, mm = mi & 15;
        float2 xv = *(const float2*)&x_lds[gg * 16448 + mm * 1028 + tid * 2];
        const f32x4* pp = (const f32x4*)&p_lds[gg * 256 + mm * 16];
        #pragma unroll
        for (int gq = 0; gq < 4; gq++) {
            f32x4 pv = pp[gq];
            acc[(gq * 4 + 0) * 2 + 0] += pv[0] * xv.x;
            acc[(gq * 4 + 0) * 2 + 1] += pv[0] * xv.y;
            acc[(gq * 4 + 1) * 2 + 0] += pv[1] * xv.x;
            acc[(gq * 4 + 1) * 2 + 1] += pv[1] * xv.y;
            acc[(gq * 4 + 2) * 2 + 0] += pv[2] * xv.x;
            acc[(gq * 4 + 2) * 2 + 1] += pv[2] * xv.y;
            acc[(gq * 4 + 3) * 2 + 0] += pv[3] * xv.x;
            acc[(gq * 4 + 3) * 2 + 1] += pv[3] * xv.y;
        }
    }

    // store partials as packed bf16 (coalesced dwords, no atomics)
    #pragma unroll
    for (int h = 0; h < 16; h++) {
        unsigned int pk = (unsigned int)f2bf(acc[h * 2])
                        | ((unsigned int)f2bf(acc[h * 2 + 1]) << 16);
        partial_bf[(beta * 16 + h) * 512 + tid] = pk;
    }
    if (tid < 16) atomicAdd(&S_shard[(beta & 15) * 16 + tid], esum[tid]);
}

// k3: u cols via uint2 loads. 64 blocks x 512 thr; each lane owns one uint2
// column (4 fp32 outputs), waves stripe the 256 chunks.
__global__ __launch_bounds__(512) void k3_reduce(
    const uint2* __restrict__ partial_u2, f32x4* __restrict__ u_ws4)
{
    __shared__ float red[8][64][4];
    int wave = threadIdx.x >> 6, lane = threadIdx.x & 63;
    int col2 = blockIdx.x * 64 + lane;       // 0..4095 uint2 columns
    float s0 = 0.f, s1 = 0.f, s2 = 0.f, s3 = 0.f;
    #pragma unroll 8
    for (int bb = wave; bb < 256; bb += 8) {
        uint2 v = partial_u2[bb * 4096 + col2];
        s0 += bf2f(v.x); s1 += bf2f(v.x >> 16);
        s2 += bf2f(v.y); s3 += bf2f(v.y >> 16);
    }
    red[wave][lane][0] = s0; red[wave][lane][1] = s1;
    red[wave][lane][2] = s2; red[wave][lane][3] = s3;
    __syncthreads();
    if (wave == 0) {
        f32x4 t = {0.f, 0.f, 0.f, 0.f};
        #pragma unroll
        for (int w = 0; w < 8; w++) {
            t[0] += red[w][lane][0]; t[1] += red[w][lane][1];
            t[2] += red[w][lane][2]; t[3] += red[w][lane][3];
        }
        u_ws4[col2] = t;
    }
}

// k4: oh[i] = (Wv[i,:].u_h)/S_h + bv[i]. One wave per output.
__global__ __launch_bounds__(256) void k4_oh(
    const float* __restrict__ W, const float* __restrict__ bias,
    const float* __restrict__ u_ws, const float* __restrict__ S_shard,
    float* __restrict__ oh_ws)
{
    int wave = threadIdx.x >> 6, lane = threadIdx.x & 63;
    int i = blockIdx.x * 4 + wave;
    int h = i >> 6;
    float Sh = 0.f;
    #pragma unroll
    for (int sh = 0; sh < NSHARD; sh++) Sh += S_shard[sh * 16 + h];
    const f32x4* wp = (const f32x4*)(W + (2 * E + i) * E) + lane * 4;
    const f32x4* up = (const f32x4*)(u_ws + h * E) + lane * 4;
    float s = 0.f;
    #pragma unroll
    for (int j = 0; j < 4; j++) {
        f32x4 w4 = wp[j], u4 = up[j];
        s += w4[0]*u4[0] + w4[1]*u4[1] + w4[2]*u4[2] + w4[3]*u4[3];
    }
    s = wave_reduce_sum(s);
    if (lane == 0) oh_ws[i] = s / Sh + bias[2 * E + i];
}

// k5: out[j] = Wout[j,:].oh + bout[j]. One wave per output.
__global__ __launch_bounds__(256) void k5_out(
    const float* __restrict__ Wout, const float* __restrict__ bout,
    const float* __restrict__ oh_ws, float* __restrict__ out)
{
    int wave = threadIdx.x >> 6, lane = threadIdx.x & 63;
    int j = blockIdx.x * 4 + wave;
    const f32x4* wp = (const f32x4*)(Wout + j * E) + lane * 4;
    const f32x4* op = (const f32x4*)(oh_ws) + lane * 4;
    float s = 0.f;
    #pragma unroll
    for (int jj = 0; jj < 4; jj++) {
        f32x4 w4 = wp[jj], o4 = op[jj];
        s += w4[0]*o4[0] + w4[1]*o4[1] + w4[2]*o4[2] + w4[3]*o4[3];
    }
    s = wave_reduce_sum(s);
    if (lane == 0) out[j] = s + bout[j];
}

extern "C" void kernel_launch(void* const* d_in, const int* in_sizes, int n_in,
                              void* d_out, int out_size, void* d_ws, size_t ws_size,
                              hipStream_t stream) {
    const float* x  = (const float*)d_in[0];
    const float* W  = (const float*)d_in[1];
    const float* b  = (const float*)d_in[2];
    const float* Wo = (const float*)d_in[3];
    const float* bo = (const float*)d_in[4];
    float* out = (float*)d_out;
    char* ws = (char*)d_ws;

    float* c_ws    = (float*)(ws);                  // 64 B
    float* S_shard = (float*)(ws + 1024);           // 1 KB (16 shards x 16 h)
    float* oh_ws   = (float*)(ws + 4096);           // 4 KB
    float* q_ws    = (float*)(ws + 12288);          // 4 KB
    unsigned short* r_bf = (unsigned short*)(ws + 16384); // 32 KB
    float* u_ws    = (float*)(ws + 65536);          // 64 KB
    unsigned int* partial_bf = (unsigned int*)(ws + 131072);  // 8 MB

    hipLaunchKernelGGL(k0_q,     dim3(256), dim3(256), 0, stream,
                       x, W, b, q_ws, S_shard);
    hipLaunchKernelGGL(k1_rc,    dim3(256), dim3(256), 0, stream,
                       W, b, q_ws, r_bf, c_ws);
    hipLaunchKernelGGL(k2_fused, dim3(256), dim3(512), 0, stream,
                       x, r_bf, c_ws, partial_bf, S_shard);
    hipLaunchKernelGGL(k3_reduce, dim3(64), dim3(512), 0, stream,
                       (const uint2*)partial_bf, (f32x4*)u_ws);
    hipLaunchKernelGGL(k4_oh,    dim3(256), dim3(256), 0, stream,
                       W, b, u_ws, S_shard, oh_ws);
    hipLaunchKernelGGL(k5_out,   dim3(256), dim3(256), 0, stream,
                       Wo, bo, oh_ws, out);
}